// Round 8
// baseline (95.117 us; speedup 1.0000x reference)
//
#include <hip/hip_runtime.h>
#include <math.h>

// Problem constants: R=4, I=16, N=2048.
#define RDIM 4
#define IDIM 16
#define NPAIR 64
#define NPTS 2048
#define THREADS 256
#define ROWSB 256                   // target rows per block (64 per wave)
#define RBLK (NPTS / ROWSB)         // 8
#define TILES (NPTS / 32)           // 64 col-tiles of 32
#define PSPLIT 4                    // prep parallelism split
#define ONEBF 0x3F80u               // bf16(1.0)

typedef __attribute__((ext_vector_type(8))) short bf16x8;
typedef __attribute__((ext_vector_type(16))) float f32x16;
typedef __attribute__((ext_vector_type(4))) float f32x4;

// fminf chain -> backend can fuse to v_min3_f32; no inline asm.
__device__ __forceinline__ float min3f(float a, float b, float c) {
    return fminf(a, fminf(b, c));
}

// Order-preserving float -> uint key (handles tiny negatives from rounding).
__device__ __forceinline__ unsigned int fkey(float f) {
    const unsigned int u = __float_as_uint(f);
    return (u & 0x80000000u) ? ~u : (u | 0x80000000u);
}
__device__ __forceinline__ float funkey(unsigned int k) {
    const unsigned int u = (k & 0x80000000u) ? (k ^ 0x80000000u) : ~k;
    return __uint_as_float(u);
}

__device__ __forceinline__ unsigned int f2bf(float f) {
    union { float f; unsigned int u; } v; v.f = f;
    return (v.u + 0x7FFFu + ((v.u >> 16) & 1u)) >> 16;   // RNE bf16 (low 16 bits)
}
__device__ __forceinline__ float bf2f(unsigned int h) {
    union { unsigned int u; float f; } v; v.u = h << 16; return v.f;
}

__device__ __forceinline__ void make_rot(const float* __restrict__ rotv, int pair,
                                         float& r00, float& r01, float& r02,
                                         float& r10, float& r11, float& r12,
                                         float& r20, float& r21, float& r22) {
    const float ax = rotv[pair * 3 + 0];
    const float ay = rotv[pair * 3 + 1];
    const float az = rotv[pair * 3 + 2];
    float sx, cx, sy, cy, sz, cz;
    sincosf(ax, &sx, &cx);
    sincosf(ay, &sy, &cy);
    sincosf(az, &sz, &cz);
    r00 = cy * cz;                r01 = -cy * sz;               r02 = sy;
    r10 = cx * sz + sx * sy * cz; r11 = cx * cz - sx * sy * sz; r12 = -sx * cy;
    r20 = sx * sz - cx * sy * cz; r21 = sx * cz + cx * sy * sz; r22 = cx * cy;
}

// B-record (16 B): shorts [bh0,bh1,bh2, bl0,bl1,bl2, n2h, n2l],  b = split(-2v), n2 = |v|^2
__device__ __forceinline__ uint4 brec(float v0, float v1, float v2) {
    const float b0 = -2.0f * v0, b1 = -2.0f * v1, b2 = -2.0f * v2;
    const unsigned int h0 = f2bf(b0), h1 = f2bf(b1), h2 = f2bf(b2);
    const unsigned int l0 = f2bf(b0 - bf2f(h0));
    const unsigned int l1 = f2bf(b1 - bf2f(h1));
    const unsigned int l2 = f2bf(b2 - bf2f(h2));
    const float n2 = v0 * v0 + v1 * v1 + v2 * v2;
    const unsigned int nh = f2bf(n2), nl = f2bf(n2 - bf2f(nh));
    return make_uint4(h0 | (h1 << 16), h2 | (l0 << 16), l1 | (l2 << 16), nh | (nl << 16));
}
// A-record (32 B): half0 = [qh0,qh1,qh2, ql0,ql1,ql2, 1, 0]
//                  half1 = [ql0,ql1,ql2, qh0,qh1,qh2, 0, 1]
// K=16 across both halves vs broadcast B=[rec|rec]:
// A.B = (qh+ql).(bh+bl) + n2h + n2l = -2 q.v + |v|^2   (exact to ~1e-5)
__device__ __forceinline__ void arec(float q0, float q1, float q2, uint4& a0, uint4& a1) {
    const unsigned int h0 = f2bf(q0), h1 = f2bf(q1), h2 = f2bf(q2);
    const unsigned int l0 = f2bf(q0 - bf2f(h0));
    const unsigned int l1 = f2bf(q1 - bf2f(h1));
    const unsigned int l2 = f2bf(q2 - bf2f(h2));
    a0 = make_uint4(h0 | (h1 << 16), h2 | (l0 << 16), l1 | (l2 << 16), ONEBF);
    a1 = make_uint4(l0 | (l1 << 16), l2 | (h0 << 16), h1 | (h2 << 16), ONEBF << 16);
}

// K0: grid (80, PSPLIT).
//   x-blocks 0..63 (pair): transformed source -> Yb records; init colminU[pair][*] = max
//   x-blocks 64..79 (i):   target            -> Xa records
// Block (0,0) also zeroes the output.
__global__ __launch_bounds__(THREADS)
void prep(const float* __restrict__ src, const float* __restrict__ tgt,
          const float* __restrict__ rotv, const float* __restrict__ trav,
          const float* __restrict__ scal,
          uint4* __restrict__ Yb, uint4* __restrict__ Xa,
          unsigned int* __restrict__ colminU,
          float* __restrict__ out)
{
    const int b   = blockIdx.x;
    const int seg = blockIdx.y;
    const int tid = threadIdx.x;
    if (b == 0 && seg == 0 && tid < NPAIR) out[tid] = 0.0f;
    const int m0  = seg * (NPTS / PSPLIT);
    if (b < NPAIR) {
        const int pair = b;
        colminU[(size_t)pair * NPTS + m0 + tid * 2 + 0] = 0xFFFFFFFFu;
        colminU[(size_t)pair * NPTS + m0 + tid * 2 + 1] = 0xFFFFFFFFu;
        float r00, r01, r02, r10, r11, r12, r20, r21, r22;
        make_rot(rotv, pair, r00, r01, r02, r10, r11, r12, r20, r21, r22);
        const float t0 = trav[pair * 3 + 0];
        const float t1 = trav[pair * 3 + 1];
        const float t2 = trav[pair * 3 + 2];
        const float s  = scal[pair];
        const float* __restrict__ srcp = src + (size_t)pair * NPTS * 3;
#pragma unroll
        for (int u = 0; u < NPTS / THREADS / PSPLIT; ++u) {
            const int m = m0 + u * THREADS + tid;
            const float p0 = srcp[m * 3 + 0];
            const float p1 = srcp[m * 3 + 1];
            const float p2 = srcp[m * 3 + 2];
            const float y0 = s * fmaf(r00, p0, fmaf(r01, p1, fmaf(r02, p2, t0)));
            const float y1 = s * fmaf(r10, p0, fmaf(r11, p1, fmaf(r12, p2, t1)));
            const float y2 = s * fmaf(r20, p0, fmaf(r21, p1, fmaf(r22, p2, t2)));
            Yb[(size_t)pair * NPTS + m] = brec(y0, y1, y2);
        }
    } else {
        const int i = b - NPAIR;
        const float* __restrict__ tgtp = tgt + (size_t)i * NPTS * 3;
#pragma unroll
        for (int u = 0; u < NPTS / THREADS / PSPLIT; ++u) {
            const int m = m0 + u * THREADS + tid;
            const float x0 = tgtp[m * 3 + 0];
            const float x1 = tgtp[m * 3 + 1];
            const float x2 = tgtp[m * 3 + 2];
            uint4 a0, a1;
            arec(x0, x1, x2, a0, a1);
            Xa[((size_t)i * NPTS + m) * 2 + 0] = a0;
            Xa[((size_t)i * NPTS + m) * 2 + 1] = a1;
        }
    }
}

// K1: SINGLE PASS, grid (pair, rb) = 512 blocks (fully resident at 2/CU).
// rows = target (Xa, 256/block), cols = ALL transformed (Yb, 2048 staged in sB).
// KEY FIX vs R7: the MFMA C operand carries |x|^2 per OUTPUT ROW (C layout == D
// layout, row depends only on (j,h,rt)), so D = -2x.y + |y|^2 + |x|^2 = FULL
// squared distance. Both min directions are then correct with zero extra
// inner-loop VALU; cham_x tail and K2 need no norm adds.
// __launch_bounds__(256,2): 256-reg cap, no AGPR-bounce risk (live set ~170).
__global__ __launch_bounds__(THREADS, 2)
void chamfer_main(const uint4* __restrict__ Yb, const uint4* __restrict__ Xa,
                  unsigned int* __restrict__ colminU,
                  float* __restrict__ out)
{
    __shared__ alignas(16) unsigned char smem[32768];  // sB: 2048 recs x 16 B
    __shared__ unsigned int colpartU[NPTS];            // 8 KB: block col-min keys
    __shared__ float sx[ROWSB];                        // 1 KB: |x|^2 per block row
    __shared__ float rowmin[ROWSB];
    __shared__ float wsum[4];
    unsigned short* sB = (unsigned short*)smem;        // [2048][8] shorts

    const int pair  = blockIdx.x;
    const int rb    = blockIdx.y;
    const int i     = pair & (IDIM - 1);
    const int tid   = threadIdx.x;
    const int lane  = tid & 63;
    const int w     = tid >> 6;
    const int c31   = lane & 31;   // column within 32-tile
    const int h     = lane >> 5;   // K-half / row-subgroup select

    const uint4* __restrict__ gB = Yb + (size_t)pair * NPTS;
    const char* gAb = (const char*)(Xa + ((size_t)i * NPTS + rb * ROWSB) * 2);

    // ---- stage sB (8 uint4/thread), init colpartU (8/thread), build sx[tid] ----
#pragma unroll
    for (int j = 0; j < 8; ++j)
        ((uint4*)sB)[j * THREADS + tid] = gB[j * THREADS + tid];
#pragma unroll
    for (int k = 0; k < 8; ++k)
        colpartU[k * THREADS + tid] = 0xFFFFFFFFu;
    {
        const unsigned short* ar = (const unsigned short*)(gAb + tid * 32);
        const float q0 = bf2f(ar[0]) + bf2f(ar[3]);
        const float q1 = bf2f(ar[1]) + bf2f(ar[4]);
        const float q2 = bf2f(ar[2]) + bf2f(ar[5]);
        sx[tid] = q0 * q0 + q1 * q1 + q2 * q2;
    }

    // ---- A fragments from global: wave w rows [w*64, w*64+64), 2 row-tiles of 32 ----
    const bf16x8 af0 = *(const bf16x8*)(gAb + (w * 64 + c31) * 32 + h * 16);
    const bf16x8 af1 = *(const bf16x8*)(gAb + (w * 64 + 32 + c31) * 32 + h * 16);

    __syncthreads();

    // ---- C operands: |x|^2 at D-layout rows (m74/m101: row = (j&3)+8*(j>>2)+4h) ----
    f32x16 cx0, cx1;
#pragma unroll
    for (int j = 0; j < 16; ++j) {
        const int r = (j & 3) + 8 * (j >> 2) + 4 * h;
        cx0[j] = sx[w * 64 + r];
        cx1[j] = sx[w * 64 + 32 + r];
    }

    float mn0[16], mn1[16];
#pragma unroll
    for (int j = 0; j < 16; ++j) { mn0[j] = 3.4e38f; mn1[j] = 3.4e38f; }

    // ---- main loop: 64 col-tiles in pairs, bf prefetched one pair ahead ----
    bf16x8 bfA = *(const bf16x8*)&sB[(0 * 32 + c31) * 8];
    bf16x8 bfB = *(const bf16x8*)&sB[(1 * 32 + c31) * 8];
    for (int t = 0; t < TILES; t += 2) {
        const f32x16 a0 = __builtin_amdgcn_mfma_f32_32x32x16_bf16(af0, bfA, cx0, 0, 0, 0);
        const f32x16 a1 = __builtin_amdgcn_mfma_f32_32x32x16_bf16(af1, bfA, cx1, 0, 0, 0);
        const f32x16 b0 = __builtin_amdgcn_mfma_f32_32x32x16_bf16(af0, bfB, cx0, 0, 0, 0);
        const f32x16 b1 = __builtin_amdgcn_mfma_f32_32x32x16_bf16(af1, bfB, cx1, 0, 0, 0);
        // prefetch next tile pair (wrap keeps it branchless + in-bounds)
        bfA = *(const bf16x8*)&sB[((((t + 2) & 63)) * 32 + c31) * 8];
        bfB = *(const bf16x8*)&sB[((((t + 3) & 63)) * 32 + c31) * 8];
        // row-direction fold (cham_x): min over cols, per row
#pragma unroll
        for (int j = 0; j < 16; ++j) {
            mn0[j] = min3f(mn0[j], a0[j], b0[j]);
            mn1[j] = min3f(mn1[j], a1[j], b1[j]);
        }
        // col-direction fold (cham_y): min over the wave's 64 rows, per col
        float ca = fminf(a0[0], a1[0]);
        float cb = fminf(b0[0], b1[0]);
#pragma unroll
        for (int j = 1; j < 16; ++j) {
            ca = min3f(ca, a0[j], a1[j]);
            cb = min3f(cb, b0[j], b1[j]);
        }
        ca = fminf(ca, __shfl_xor(ca, 32, 64));
        cb = fminf(cb, __shfl_xor(cb, 32, 64));
        if (h == 0) {
            atomicMin(&colpartU[(t + 0) * 32 + c31], fkey(ca));
            atomicMin(&colpartU[(t + 1) * 32 + c31], fkey(cb));
        }
    }
    __syncthreads();   // colpartU complete across waves

    // ---- row endgame: butterfly over the 32 column-lanes ----
#pragma unroll
    for (int j = 0; j < 16; ++j) {
        float v0 = mn0[j], v1 = mn1[j];
        v0 = fminf(v0, __shfl_xor(v0, 1, 64));
        v1 = fminf(v1, __shfl_xor(v1, 1, 64));
        v0 = fminf(v0, __shfl_xor(v0, 2, 64));
        v1 = fminf(v1, __shfl_xor(v1, 2, 64));
        v0 = fminf(v0, __shfl_xor(v0, 4, 64));
        v1 = fminf(v1, __shfl_xor(v1, 4, 64));
        v0 = fminf(v0, __shfl_xor(v0, 8, 64));
        v1 = fminf(v1, __shfl_xor(v1, 8, 64));
        v0 = fminf(v0, __shfl_xor(v0, 16, 64));
        v1 = fminf(v1, __shfl_xor(v1, 16, 64));
        mn0[j] = v0; mn1[j] = v1;
    }
    if (c31 == 0) {
#pragma unroll
        for (int g = 0; g < 4; ++g) {
            f32x4 v4, u4;
            v4[0] = mn0[g * 4 + 0]; v4[1] = mn0[g * 4 + 1];
            v4[2] = mn0[g * 4 + 2]; v4[3] = mn0[g * 4 + 3];
            u4[0] = mn1[g * 4 + 0]; u4[1] = mn1[g * 4 + 1];
            u4[2] = mn1[g * 4 + 2]; u4[3] = mn1[g * 4 + 3];
            *(f32x4*)&rowmin[w * 64 + 8 * g + 4 * h] = v4;
            *(f32x4*)&rowmin[w * 64 + 32 + 8 * g + 4 * h] = u4;
        }
    }

    // ---- col partials -> global keys (8 per thread) ----
#pragma unroll
    for (int k = 0; k < 8; ++k) {
        const int col = k * THREADS + tid;
        atomicMin(&colminU[(size_t)pair * NPTS + col], colpartU[col]);
    }
    __syncthreads();   // rowmin visible

    // ---- cham_x tail: rowmin already holds full |x-y|^2 (C carried |x|^2) ----
    float v = rowmin[tid];
#pragma unroll
    for (int off = 32; off > 0; off >>= 1)
        v += __shfl_down(v, off, 64);
    if (lane == 0) wsum[w] = v;
    __syncthreads();
    if (tid == 0) {
        const float tot = wsum[0] + wsum[1] + wsum[2] + wsum[3];
        atomicAdd(&out[pair], tot * (1.0f / NPTS));
    }
}

// K2: cham_y finalize. Keys already hold full |x-y|^2 minima; decode + mean.
__global__ __launch_bounds__(THREADS)
void chamfer_col(const unsigned int* __restrict__ colminU, float* __restrict__ out)
{
    __shared__ float wsum[4];
    const int pair = blockIdx.x;
    const int tid  = threadIdx.x;
    const int lane = tid & 63;
    const int w    = tid >> 6;
    float s = 0.0f;
#pragma unroll
    for (int k = 0; k < 8; ++k) {
        const int col = k * THREADS + tid;
        s += funkey(colminU[(size_t)pair * NPTS + col]);
    }
#pragma unroll
    for (int off = 32; off > 0; off >>= 1)
        s += __shfl_down(s, off, 64);
    if (lane == 0) wsum[w] = s;
    __syncthreads();
    if (tid == 0) {
        const float tot = wsum[0] + wsum[1] + wsum[2] + wsum[3];
        atomicAdd(&out[pair], tot * (1.0f / NPTS));
    }
}

extern "C" void kernel_launch(void* const* d_in, const int* in_sizes, int n_in,
                              void* d_out, int out_size, void* d_ws, size_t ws_size,
                              hipStream_t stream) {
    const float* src  = (const float*)d_in[0];  // [4,16,2048,3]
    const float* tgt  = (const float*)d_in[1];  // [16,2048,3]
    const float* rotv = (const float*)d_in[2];  // [4,16,3]
    const float* trav = (const float*)d_in[3];  // [4,16,3]
    const float* scal = (const float*)d_in[4];  // [4,16]
    float* out = (float*)d_out;                 // [4,16]

    // ws: Yb 2 MB | Xa 1 MB | colminU 0.5 MB
    char* ws = (char*)d_ws;
    uint4* Yb = (uint4*)ws;
    uint4* Xa = (uint4*)(ws + (size_t)NPAIR * NPTS * 16);
    unsigned int* colminU = (unsigned int*)(ws + (size_t)NPAIR * NPTS * 16
                                               + (size_t)IDIM * NPTS * 32);

    dim3 pgrid(NPAIR + IDIM, PSPLIT);
    prep<<<pgrid, THREADS, 0, stream>>>(src, tgt, rotv, trav, scal, Yb, Xa, colminU, out);

    dim3 grid(NPAIR, RBLK);
    chamfer_main<<<grid, THREADS, 0, stream>>>(Yb, Xa, colminU, out);

    chamfer_col<<<NPAIR, THREADS, 0, stream>>>(colminU, out);
}

// Round 9
// 92.955 us; speedup vs baseline: 1.0233x; 1.0233x over previous
//
#include <hip/hip_runtime.h>
#include <math.h>

// Problem constants: R=4, I=16, N=2048.
#define RDIM 4
#define IDIM 16
#define NPAIR 64
#define NPTS 2048
#define THREADS 256
#define ROWSB 256                   // target rows per block (64 per wave)
#define RBLK (NPTS / ROWSB)         // 8
#define TILES (NPTS / 32)           // 64 col-tiles of 32
#define ONEBF 0x3F80u               // bf16(1.0)

typedef __attribute__((ext_vector_type(8))) short bf16x8;
typedef __attribute__((ext_vector_type(16))) float f32x16;
typedef __attribute__((ext_vector_type(4))) float f32x4;

// fminf chain -> backend can fuse to v_min3_f32; no inline asm.
__device__ __forceinline__ float min3f(float a, float b, float c) {
    return fminf(a, fminf(b, c));
}

// Order-preserving float -> uint key (handles tiny negatives from rounding).
__device__ __forceinline__ unsigned int fkey(float f) {
    const unsigned int u = __float_as_uint(f);
    return (u & 0x80000000u) ? ~u : (u | 0x80000000u);
}
__device__ __forceinline__ float funkey(unsigned int k) {
    const unsigned int u = (k & 0x80000000u) ? (k ^ 0x80000000u) : ~k;
    return __uint_as_float(u);
}

__device__ __forceinline__ unsigned int f2bf(float f) {
    union { float f; unsigned int u; } v; v.f = f;
    return (v.u + 0x7FFFu + ((v.u >> 16) & 1u)) >> 16;   // RNE bf16 (low 16 bits)
}
__device__ __forceinline__ float bf2f(unsigned int h) {
    union { unsigned int u; float f; } v; v.u = h << 16; return v.f;
}

__device__ __forceinline__ void make_rot(const float* __restrict__ rotv, int pair,
                                         float& r00, float& r01, float& r02,
                                         float& r10, float& r11, float& r12,
                                         float& r20, float& r21, float& r22) {
    const float ax = rotv[pair * 3 + 0];
    const float ay = rotv[pair * 3 + 1];
    const float az = rotv[pair * 3 + 2];
    float sx, cx, sy, cy, sz, cz;
    sincosf(ax, &sx, &cx);
    sincosf(ay, &sy, &cy);
    sincosf(az, &sz, &cz);
    r00 = cy * cz;                r01 = -cy * sz;               r02 = sy;
    r10 = cx * sz + sx * sy * cz; r11 = cx * cz - sx * sy * sz; r12 = -sx * cy;
    r20 = sx * sz - cx * sy * cz; r21 = sx * cz + cx * sy * sz; r22 = cx * cy;
}

// B-record (16 B): shorts [bh0,bh1,bh2, bl0,bl1,bl2, n2h, n2l],  b = split(-2v), n2 = |v|^2
__device__ __forceinline__ uint4 brec(float v0, float v1, float v2) {
    const float b0 = -2.0f * v0, b1 = -2.0f * v1, b2 = -2.0f * v2;
    const unsigned int h0 = f2bf(b0), h1 = f2bf(b1), h2 = f2bf(b2);
    const unsigned int l0 = f2bf(b0 - bf2f(h0));
    const unsigned int l1 = f2bf(b1 - bf2f(h1));
    const unsigned int l2 = f2bf(b2 - bf2f(h2));
    const float n2 = v0 * v0 + v1 * v1 + v2 * v2;
    const unsigned int nh = f2bf(n2), nl = f2bf(n2 - bf2f(nh));
    return make_uint4(h0 | (h1 << 16), h2 | (l0 << 16), l1 | (l2 << 16), nh | (nl << 16));
}
// A-record (32 B): half0 = [qh0,qh1,qh2, ql0,ql1,ql2, 1, 0]
//                  half1 = [ql0,ql1,ql2, qh0,qh1,qh2, 0, 1]
// K=16 across both halves vs broadcast B=[rec|rec]:
// A.B = (qh+ql).(bh+bl) + n2h + n2l = -2 q.v + |v|^2   (exact to ~1e-5)
__device__ __forceinline__ void arec(float q0, float q1, float q2, uint4& a0, uint4& a1,
                                     float& qn2) {
    const unsigned int h0 = f2bf(q0), h1 = f2bf(q1), h2 = f2bf(q2);
    const unsigned int l0 = f2bf(q0 - bf2f(h0));
    const unsigned int l1 = f2bf(q1 - bf2f(h1));
    const unsigned int l2 = f2bf(q2 - bf2f(h2));
    a0 = make_uint4(h0 | (h1 << 16), h2 | (l0 << 16), l1 | (l2 << 16), ONEBF);
    a1 = make_uint4(l0 | (l1 << 16), l2 | (h0 << 16), h1 | (h2 << 16), ONEBF << 16);
    // |x|^2 from the SAME rounded values the records carry (matches R8's decode).
    const float d0 = bf2f(h0) + bf2f(l0);
    const float d1 = bf2f(h1) + bf2f(l1);
    const float d2 = bf2f(h2) + bf2f(l2);
    qn2 = d0 * d0 + d1 * d1 + d2 * d2;
}

// K1: single pass, NO prep kernel, NO atomics. Grid (pair, rb) = 512 blocks.
// Each block builds its own staging in-block (bit-identical record code):
//   sB: all 2048 transformed-source B-records for its pair (brec of transform)
//   sA: its 256 target A-records (arec), sx: |x|^2 per row
// MFMA C operand carries |x|^2 per output row (R8-verified) -> D = full |x-y|^2.
// Outputs: rowpart[pair][rb] (block row-min sum, plain store) and
//          colkeys[pair][rb][2048] (block col-min keys, plain store).
__global__ __launch_bounds__(THREADS, 2)
void chamfer_main(const float* __restrict__ src, const float* __restrict__ tgt,
                  const float* __restrict__ rotv, const float* __restrict__ trav,
                  const float* __restrict__ scal,
                  unsigned int* __restrict__ colkeys,
                  float* __restrict__ rowpart)
{
    __shared__ alignas(16) unsigned char smem[32768];  // sB: 2048 recs x 16 B
    __shared__ alignas(16) uint4 sA[ROWSB * 2];        // 8 KB: 256 A-records
    __shared__ unsigned int colpartU[NPTS];            // 8 KB: block col-min keys
    __shared__ float sx[ROWSB];                        // 1 KB: |x|^2 per block row
    __shared__ float rowmin[ROWSB];
    __shared__ float wsum[4];
    unsigned short* sB = (unsigned short*)smem;        // [2048][8] shorts

    const int pair  = blockIdx.x;
    const int rb    = blockIdx.y;
    const int i     = pair & (IDIM - 1);
    const int tid   = threadIdx.x;
    const int lane  = tid & 63;
    const int w     = tid >> 6;
    const int c31   = lane & 31;   // column within 32-tile
    const int h     = lane >> 5;   // K-half / row-subgroup select

    // ---- in-block transform + staging ----
    {
        float r00, r01, r02, r10, r11, r12, r20, r21, r22;
        make_rot(rotv, pair, r00, r01, r02, r10, r11, r12, r20, r21, r22);
        const float t0 = trav[pair * 3 + 0];
        const float t1 = trav[pair * 3 + 1];
        const float t2 = trav[pair * 3 + 2];
        const float s  = scal[pair];
        const float* __restrict__ srcp = src + (size_t)pair * NPTS * 3;
#pragma unroll
        for (int u = 0; u < NPTS / THREADS; ++u) {
            const int m = u * THREADS + tid;
            const float p0 = srcp[m * 3 + 0];
            const float p1 = srcp[m * 3 + 1];
            const float p2 = srcp[m * 3 + 2];
            const float y0 = s * fmaf(r00, p0, fmaf(r01, p1, fmaf(r02, p2, t0)));
            const float y1 = s * fmaf(r10, p0, fmaf(r11, p1, fmaf(r12, p2, t1)));
            const float y2 = s * fmaf(r20, p0, fmaf(r21, p1, fmaf(r22, p2, t2)));
            ((uint4*)sB)[m] = brec(y0, y1, y2);
        }
        // this block's 256 target rows -> A-records + |x|^2
        const float* __restrict__ tgtp = tgt + ((size_t)i * NPTS + rb * ROWSB) * 3;
        const float x0 = tgtp[tid * 3 + 0];
        const float x1 = tgtp[tid * 3 + 1];
        const float x2 = tgtp[tid * 3 + 2];
        uint4 a0, a1; float qn2;
        arec(x0, x1, x2, a0, a1, qn2);
        sA[tid * 2 + 0] = a0;
        sA[tid * 2 + 1] = a1;
        sx[tid] = qn2;
    }
#pragma unroll
    for (int k = 0; k < 8; ++k)
        colpartU[k * THREADS + tid] = 0xFFFFFFFFu;
    __syncthreads();

    // ---- A fragments: wave w rows [w*64, w*64+64), 2 row-tiles of 32 ----
    const unsigned short* sAs = (const unsigned short*)sA;   // [256][16] shorts
    const bf16x8 af0 = *(const bf16x8*)&sAs[(w * 64 + c31) * 16 + h * 8];
    const bf16x8 af1 = *(const bf16x8*)&sAs[(w * 64 + 32 + c31) * 16 + h * 8];

    // ---- C operands: |x|^2 at D-layout rows (m74/m101: row = (j&3)+8*(j>>2)+4h) ----
    f32x16 cx0, cx1;
#pragma unroll
    for (int j = 0; j < 16; ++j) {
        const int r = (j & 3) + 8 * (j >> 2) + 4 * h;
        cx0[j] = sx[w * 64 + r];
        cx1[j] = sx[w * 64 + 32 + r];
    }

    float mn0[16], mn1[16];
#pragma unroll
    for (int j = 0; j < 16; ++j) { mn0[j] = 3.4e38f; mn1[j] = 3.4e38f; }

    // ---- main loop: 64 col-tiles in pairs, bf prefetched one pair ahead ----
    bf16x8 bfA = *(const bf16x8*)&sB[(0 * 32 + c31) * 8];
    bf16x8 bfB = *(const bf16x8*)&sB[(1 * 32 + c31) * 8];
    for (int t = 0; t < TILES; t += 2) {
        const f32x16 a0 = __builtin_amdgcn_mfma_f32_32x32x16_bf16(af0, bfA, cx0, 0, 0, 0);
        const f32x16 a1 = __builtin_amdgcn_mfma_f32_32x32x16_bf16(af1, bfA, cx1, 0, 0, 0);
        const f32x16 b0 = __builtin_amdgcn_mfma_f32_32x32x16_bf16(af0, bfB, cx0, 0, 0, 0);
        const f32x16 b1 = __builtin_amdgcn_mfma_f32_32x32x16_bf16(af1, bfB, cx1, 0, 0, 0);
        // prefetch next tile pair (wrap keeps it branchless + in-bounds)
        bfA = *(const bf16x8*)&sB[((((t + 2) & 63)) * 32 + c31) * 8];
        bfB = *(const bf16x8*)&sB[((((t + 3) & 63)) * 32 + c31) * 8];
        // row-direction fold (cham_x): min over cols, per row
#pragma unroll
        for (int j = 0; j < 16; ++j) {
            mn0[j] = min3f(mn0[j], a0[j], b0[j]);
            mn1[j] = min3f(mn1[j], a1[j], b1[j]);
        }
        // col-direction fold (cham_y): min over the wave's 64 rows, per col
        float ca = fminf(a0[0], a1[0]);
        float cb = fminf(b0[0], b1[0]);
#pragma unroll
        for (int j = 1; j < 16; ++j) {
            ca = min3f(ca, a0[j], a1[j]);
            cb = min3f(cb, b0[j], b1[j]);
        }
        ca = fminf(ca, __shfl_xor(ca, 32, 64));
        cb = fminf(cb, __shfl_xor(cb, 32, 64));
        if (h == 0) {
            atomicMin(&colpartU[(t + 0) * 32 + c31], fkey(ca));
            atomicMin(&colpartU[(t + 1) * 32 + c31], fkey(cb));
        }
    }
    __syncthreads();   // colpartU complete across waves

    // ---- row endgame: butterfly over the 32 column-lanes ----
#pragma unroll
    for (int j = 0; j < 16; ++j) {
        float v0 = mn0[j], v1 = mn1[j];
        v0 = fminf(v0, __shfl_xor(v0, 1, 64));
        v1 = fminf(v1, __shfl_xor(v1, 1, 64));
        v0 = fminf(v0, __shfl_xor(v0, 2, 64));
        v1 = fminf(v1, __shfl_xor(v1, 2, 64));
        v0 = fminf(v0, __shfl_xor(v0, 4, 64));
        v1 = fminf(v1, __shfl_xor(v1, 4, 64));
        v0 = fminf(v0, __shfl_xor(v0, 8, 64));
        v1 = fminf(v1, __shfl_xor(v1, 8, 64));
        v0 = fminf(v0, __shfl_xor(v0, 16, 64));
        v1 = fminf(v1, __shfl_xor(v1, 16, 64));
        mn0[j] = v0; mn1[j] = v1;
    }
    if (c31 == 0) {
#pragma unroll
        for (int g = 0; g < 4; ++g) {
            f32x4 v4, u4;
            v4[0] = mn0[g * 4 + 0]; v4[1] = mn0[g * 4 + 1];
            v4[2] = mn0[g * 4 + 2]; v4[3] = mn0[g * 4 + 3];
            u4[0] = mn1[g * 4 + 0]; u4[1] = mn1[g * 4 + 1];
            u4[2] = mn1[g * 4 + 2]; u4[3] = mn1[g * 4 + 3];
            *(f32x4*)&rowmin[w * 64 + 8 * g + 4 * h] = v4;
            *(f32x4*)&rowmin[w * 64 + 32 + 8 * g + 4 * h] = u4;
        }
    }

    // ---- col keys -> global (plain coalesced stores, no atomics) ----
#pragma unroll
    for (int k = 0; k < 8; ++k) {
        const int col = k * THREADS + tid;
        colkeys[((size_t)pair * RBLK + rb) * NPTS + col] = colpartU[col];
    }
    __syncthreads();   // rowmin visible

    // ---- cham_x partial: block sum of full |x-y|^2 row minima ----
    float v = rowmin[tid];
#pragma unroll
    for (int off = 32; off > 0; off >>= 1)
        v += __shfl_down(v, off, 64);
    if (lane == 0) wsum[w] = v;
    __syncthreads();
    if (tid == 0)
        rowpart[pair * RBLK + rb] = wsum[0] + wsum[1] + wsum[2] + wsum[3];
}

// K2: finalize. out[pair] = (sum_rb rowpart + sum_col min_rb colkeys) / N.
// Pure write -> no atomics, no output pre-zero needed.
__global__ __launch_bounds__(THREADS)
void chamfer_fin(const unsigned int* __restrict__ colkeys,
                 const float* __restrict__ rowpart,
                 float* __restrict__ out)
{
    __shared__ float wsum[4];
    const int pair = blockIdx.x;
    const int tid  = threadIdx.x;
    const int lane = tid & 63;
    const int w    = tid >> 6;
    float s = 0.0f;
#pragma unroll
    for (int k = 0; k < 8; ++k) {
        const int col = k * THREADS + tid;
        unsigned int mk = colkeys[((size_t)pair * RBLK + 0) * NPTS + col];
#pragma unroll
        for (int rb = 1; rb < RBLK; ++rb)
            mk = min(mk, colkeys[((size_t)pair * RBLK + rb) * NPTS + col]);
        s += funkey(mk);
    }
    if (tid < RBLK) s += rowpart[pair * RBLK + tid];
#pragma unroll
    for (int off = 32; off > 0; off >>= 1)
        s += __shfl_down(s, off, 64);
    if (lane == 0) wsum[w] = s;
    __syncthreads();
    if (tid == 0)
        out[pair] = (wsum[0] + wsum[1] + wsum[2] + wsum[3]) * (1.0f / NPTS);
}

extern "C" void kernel_launch(void* const* d_in, const int* in_sizes, int n_in,
                              void* d_out, int out_size, void* d_ws, size_t ws_size,
                              hipStream_t stream) {
    const float* src  = (const float*)d_in[0];  // [4,16,2048,3]
    const float* tgt  = (const float*)d_in[1];  // [16,2048,3]
    const float* rotv = (const float*)d_in[2];  // [4,16,3]
    const float* trav = (const float*)d_in[3];  // [4,16,3]
    const float* scal = (const float*)d_in[4];  // [4,16]
    float* out = (float*)d_out;                 // [4,16]

    // ws: colkeys 4 MB | rowpart 2 KB
    char* ws = (char*)d_ws;
    unsigned int* colkeys = (unsigned int*)ws;
    float* rowpart = (float*)(ws + (size_t)NPAIR * RBLK * NPTS * 4);

    dim3 grid(NPAIR, RBLK);
    chamfer_main<<<grid, THREADS, 0, stream>>>(src, tgt, rotv, trav, scal,
                                               colkeys, rowpart);

    chamfer_fin<<<NPAIR, THREADS, 0, stream>>>(colkeys, rowpart, out);
}

// Round 10
// 88.974 us; speedup vs baseline: 1.0690x; 1.0447x over previous
//
#include <hip/hip_runtime.h>
#include <math.h>

// Problem constants: R=4, I=16, N=2048.
#define RDIM 4
#define IDIM 16
#define NPAIR 64
#define NPTS 2048
#define THREADS 256
#define ROWSB 256                   // rows per block (64 per wave)
#define RBLK (NPTS / ROWSB)         // 8
#define TILES (NPTS / 32)           // 64 col-tiles of 32
#define PSPLIT 4                    // prep parallelism split
#define ONEBF 0x3F80u               // bf16(1.0)

typedef __attribute__((ext_vector_type(8))) short bf16x8;
typedef __attribute__((ext_vector_type(16))) float f32x16;
typedef __attribute__((ext_vector_type(4))) float f32x4;

// fminf chain -> backend can fuse to v_min3_f32; no inline asm.
__device__ __forceinline__ float min3f(float a, float b, float c) {
    return fminf(a, fminf(b, c));
}

__device__ __forceinline__ unsigned int f2bf(float f) {
    union { float f; unsigned int u; } v; v.f = f;
    return (v.u + 0x7FFFu + ((v.u >> 16) & 1u)) >> 16;   // RNE bf16 (low 16 bits)
}
__device__ __forceinline__ float bf2f(unsigned int h) {
    union { unsigned int u; float f; } v; v.u = h << 16; return v.f;
}

__device__ __forceinline__ void make_rot(const float* __restrict__ rotv, int pair,
                                         float& r00, float& r01, float& r02,
                                         float& r10, float& r11, float& r12,
                                         float& r20, float& r21, float& r22) {
    const float ax = rotv[pair * 3 + 0];
    const float ay = rotv[pair * 3 + 1];
    const float az = rotv[pair * 3 + 2];
    float sx, cx, sy, cy, sz, cz;
    sincosf(ax, &sx, &cx);
    sincosf(ay, &sy, &cy);
    sincosf(az, &sz, &cz);
    r00 = cy * cz;                r01 = -cy * sz;               r02 = sy;
    r10 = cx * sz + sx * sy * cz; r11 = cx * cz - sx * sy * sz; r12 = -sx * cy;
    r20 = sx * sz - cx * sy * cz; r21 = sx * cz + cx * sy * sz; r22 = cx * cy;
}

// B-record (16 B): shorts [bh0,bh1,bh2, bl0,bl1,bl2, n2h, n2l],  b = split(-2v), n2 = |v|^2
__device__ __forceinline__ uint4 brec(float v0, float v1, float v2) {
    const float b0 = -2.0f * v0, b1 = -2.0f * v1, b2 = -2.0f * v2;
    const unsigned int h0 = f2bf(b0), h1 = f2bf(b1), h2 = f2bf(b2);
    const unsigned int l0 = f2bf(b0 - bf2f(h0));
    const unsigned int l1 = f2bf(b1 - bf2f(h1));
    const unsigned int l2 = f2bf(b2 - bf2f(h2));
    const float n2 = v0 * v0 + v1 * v1 + v2 * v2;
    const unsigned int nh = f2bf(n2), nl = f2bf(n2 - bf2f(nh));
    return make_uint4(h0 | (h1 << 16), h2 | (l0 << 16), l1 | (l2 << 16), nh | (nl << 16));
}
// A-record (32 B): half0 = [qh0,qh1,qh2, ql0,ql1,ql2, 1, 0]
//                  half1 = [ql0,ql1,ql2, qh0,qh1,qh2, 0, 1]
// K=16 across both halves vs broadcast B=[rec|rec]:
// A.B = (qh+ql).(bh+bl) + n2h + n2l = -2 q.v + |v|^2   (exact to ~1e-5)
__device__ __forceinline__ void arec(float q0, float q1, float q2, uint4& a0, uint4& a1) {
    const unsigned int h0 = f2bf(q0), h1 = f2bf(q1), h2 = f2bf(q2);
    const unsigned int l0 = f2bf(q0 - bf2f(h0));
    const unsigned int l1 = f2bf(q1 - bf2f(h1));
    const unsigned int l2 = f2bf(q2 - bf2f(h2));
    a0 = make_uint4(h0 | (h1 << 16), h2 | (l0 << 16), l1 | (l2 << 16), ONEBF);
    a1 = make_uint4(l0 | (l1 << 16), l2 | (h0 << 16), h1 | (h2 << 16), ONEBF << 16);
}

// K0: build A/B records for both point sets. Grid (80, PSPLIT).
//   x-blocks 0..63: transformed source (per pair) -> Yb, Ya
//   x-blocks 64..79: target (per i)               -> Xb, Xa
// Block (0,0) also zeroes the output (no memset dispatch).
__global__ __launch_bounds__(THREADS)
void prep(const float* __restrict__ src, const float* __restrict__ tgt,
          const float* __restrict__ rotv, const float* __restrict__ trav,
          const float* __restrict__ scal,
          uint4* __restrict__ Yb, uint4* __restrict__ Ya,
          uint4* __restrict__ Xb, uint4* __restrict__ Xa,
          float* __restrict__ out)
{
    const int b   = blockIdx.x;
    const int seg = blockIdx.y;
    const int tid = threadIdx.x;
    if (b == 0 && seg == 0 && tid < NPAIR) out[tid] = 0.0f;
    const int m0  = seg * (NPTS / PSPLIT);
    if (b < NPAIR) {
        const int pair = b;
        float r00, r01, r02, r10, r11, r12, r20, r21, r22;
        make_rot(rotv, pair, r00, r01, r02, r10, r11, r12, r20, r21, r22);
        const float t0 = trav[pair * 3 + 0];
        const float t1 = trav[pair * 3 + 1];
        const float t2 = trav[pair * 3 + 2];
        const float s  = scal[pair];
        const float* __restrict__ srcp = src + (size_t)pair * NPTS * 3;
#pragma unroll
        for (int u = 0; u < NPTS / THREADS / PSPLIT; ++u) {
            const int m = m0 + u * THREADS + tid;
            const float p0 = srcp[m * 3 + 0];
            const float p1 = srcp[m * 3 + 1];
            const float p2 = srcp[m * 3 + 2];
            const float y0 = s * fmaf(r00, p0, fmaf(r01, p1, fmaf(r02, p2, t0)));
            const float y1 = s * fmaf(r10, p0, fmaf(r11, p1, fmaf(r12, p2, t1)));
            const float y2 = s * fmaf(r20, p0, fmaf(r21, p1, fmaf(r22, p2, t2)));
            Yb[(size_t)pair * NPTS + m] = brec(y0, y1, y2);
            uint4 a0, a1;
            arec(y0, y1, y2, a0, a1);
            Ya[((size_t)pair * NPTS + m) * 2 + 0] = a0;
            Ya[((size_t)pair * NPTS + m) * 2 + 1] = a1;
        }
    } else {
        const int i = b - NPAIR;
        const float* __restrict__ tgtp = tgt + (size_t)i * NPTS * 3;
#pragma unroll
        for (int u = 0; u < NPTS / THREADS / PSPLIT; ++u) {
            const int m = m0 + u * THREADS + tid;
            const float x0 = tgtp[m * 3 + 0];
            const float x1 = tgtp[m * 3 + 1];
            const float x2 = tgtp[m * 3 + 2];
            Xb[(size_t)i * NPTS + m] = brec(x0, x1, x2);
            uint4 a0, a1;
            arec(x0, x1, x2, a0, a1);
            Xa[((size_t)i * NPTS + m) * 2 + 0] = a0;
            Xa[((size_t)i * NPTS + m) * 2 + 1] = a1;
        }
    }
}

// K1: per (pair, rowblock, pass). Each wave owns 64 rows (2 row-tiles of 32) x 2048 cols.
// R10 change vs R6 (verified 85.1): fold after each MFMA PAIR -> only 2 f32x16 in
// flight (32 VGPRs) instead of 4 (64). Live set ~110 regs; with (256,3) bounds
// (cap 170, no hard-cap trap) actual usage <=128 lets HW run 4 blocks/CU ->
// 1024-block grid in ONE residency round + 4 waves/SIMD latency hiding.
// Everything else identical to the R6 kernel (absmax 0.0 verified).
__global__ __launch_bounds__(THREADS, 3)
void chamfer_main(const uint4* __restrict__ Yb, const uint4* __restrict__ Ya,
                  const uint4* __restrict__ Xb, const uint4* __restrict__ Xa,
                  float* __restrict__ out, const float czero)
{
    __shared__ alignas(16) unsigned char smem[32768];  // sB: 2048 recs x 16 B
    __shared__ float rowmin[ROWSB];
    __shared__ float wsum[4];
    unsigned short* sB = (unsigned short*)smem;        // [2048][8] shorts

    const int pair  = blockIdx.x;
    const int rb    = blockIdx.y;
    const int passB = blockIdx.z;  // 0: rows=target, cols=transformed; 1: swapped
    const int i     = pair & (IDIM - 1);
    const int tid   = threadIdx.x;
    const int lane  = tid & 63;
    const int w     = tid >> 6;
    const int c31   = lane & 31;   // column within 32-tile
    const int h     = lane >> 5;   // K-half / row-subgroup select

    const uint4* __restrict__ gB = (passB == 0) ? (Yb + (size_t)pair * NPTS)
                                                : (Xb + (size_t)i * NPTS);
    const uint4* __restrict__ gA = (passB == 0)
        ? (Xa + ((size_t)i * NPTS + rb * ROWSB) * 2)
        : (Ya + ((size_t)pair * NPTS + rb * ROWSB) * 2);
    const char* gAb = (const char*)gA;                 // 256 rows x 32 B records

    // ---- stage sB: 2048 x 16 B (8 uint4/thread) ----
#pragma unroll
    for (int j = 0; j < 8; ++j)
        ((uint4*)sB)[j * THREADS + tid] = gB[j * THREADS + tid];

    // ---- A fragments from global: wave w rows [w*64, w*64+64), 2 row-tiles of 32 ----
    const bf16x8 af0 = *(const bf16x8*)(gAb + (w * 64 + c31) * 32 + h * 16);
    const bf16x8 af1 = *(const bf16x8*)(gAb + (w * 64 + 32 + c31) * 32 + h * 16);

    // Runtime-opaque zero C operand (resident 16 regs).
    f32x16 czv;
#pragma unroll
    for (int j = 0; j < 16; ++j) czv[j] = czero;

    float mn0[16], mn1[16];
#pragma unroll
    for (int j = 0; j < 16; ++j) { mn0[j] = 3.4e38f; mn1[j] = 3.4e38f; }

    __syncthreads();

    // ---- main loop: 64 col-tiles in pairs; fold after each MFMA pair ----
    for (int t = 0; t < TILES; t += 2) {
        const bf16x8 bfA = *(const bf16x8*)&sB[((t + 0) * 32 + c31) * 8];
        const bf16x8 bfB = *(const bf16x8*)&sB[((t + 1) * 32 + c31) * 8];
        {
            const f32x16 a0 = __builtin_amdgcn_mfma_f32_32x32x16_bf16(af0, bfA, czv, 0, 0, 0);
            const f32x16 b0 = __builtin_amdgcn_mfma_f32_32x32x16_bf16(af0, bfB, czv, 0, 0, 0);
#pragma unroll
            for (int j = 0; j < 16; ++j)
                mn0[j] = min3f(mn0[j], a0[j], b0[j]);
        }
        {
            const f32x16 a1 = __builtin_amdgcn_mfma_f32_32x32x16_bf16(af1, bfA, czv, 0, 0, 0);
            const f32x16 b1 = __builtin_amdgcn_mfma_f32_32x32x16_bf16(af1, bfB, czv, 0, 0, 0);
#pragma unroll
            for (int j = 0; j < 16; ++j)
                mn1[j] = min3f(mn1[j], a1[j], b1[j]);
        }
    }

    // ---- endgame: D layout (m74/m101): col = lane&31, row = (j&3)+8*(j>>2)+4*h.
    // Min across the 32 column-lanes: 5-step shfl_xor butterfly.
#pragma unroll
    for (int j = 0; j < 16; ++j) {
        float v0 = mn0[j], v1 = mn1[j];
        v0 = fminf(v0, __shfl_xor(v0, 1, 64));
        v1 = fminf(v1, __shfl_xor(v1, 1, 64));
        v0 = fminf(v0, __shfl_xor(v0, 2, 64));
        v1 = fminf(v1, __shfl_xor(v1, 2, 64));
        v0 = fminf(v0, __shfl_xor(v0, 4, 64));
        v1 = fminf(v1, __shfl_xor(v1, 4, 64));
        v0 = fminf(v0, __shfl_xor(v0, 8, 64));
        v1 = fminf(v1, __shfl_xor(v1, 8, 64));
        v0 = fminf(v0, __shfl_xor(v0, 16, 64));
        v1 = fminf(v1, __shfl_xor(v1, 16, 64));
        mn0[j] = v0; mn1[j] = v1;
    }

    // Lanes 0 (h=0) and 32 (h=1) publish: quad g -> rows base + 8g + 4h + {0..3}.
    if (c31 == 0) {
#pragma unroll
        for (int g = 0; g < 4; ++g) {
            f32x4 v4, u4;
            v4[0] = mn0[g * 4 + 0]; v4[1] = mn0[g * 4 + 1];
            v4[2] = mn0[g * 4 + 2]; v4[3] = mn0[g * 4 + 3];
            u4[0] = mn1[g * 4 + 0]; u4[1] = mn1[g * 4 + 1];
            u4[2] = mn1[g * 4 + 2]; u4[3] = mn1[g * 4 + 3];
            *(f32x4*)&rowmin[w * 64 + 8 * g + 4 * h] = v4;
            *(f32x4*)&rowmin[w * 64 + 32 + 8 * g + 4 * h] = u4;
        }
    }
    __syncthreads();

    // ---- tail: thread tid = block-row tid; q reconstructed from global A half0.
    const float m = rowmin[tid];
    const unsigned short* ar = (const unsigned short*)(gAb + tid * 32);
    const float q0 = bf2f(ar[0]) + bf2f(ar[3]);
    const float q1 = bf2f(ar[1]) + bf2f(ar[4]);
    const float q2 = bf2f(ar[2]) + bf2f(ar[5]);
    float v = m + q0 * q0 + q1 * q1 + q2 * q2;

#pragma unroll
    for (int off = 32; off > 0; off >>= 1)
        v += __shfl_down(v, off, 64);
    if (lane == 0) wsum[w] = v;
    __syncthreads();
    if (tid == 0) {
        const float tot = wsum[0] + wsum[1] + wsum[2] + wsum[3];
        atomicAdd(&out[pair], tot * (1.0f / NPTS));
    }
}

extern "C" void kernel_launch(void* const* d_in, const int* in_sizes, int n_in,
                              void* d_out, int out_size, void* d_ws, size_t ws_size,
                              hipStream_t stream) {
    const float* src  = (const float*)d_in[0];  // [4,16,2048,3]
    const float* tgt  = (const float*)d_in[1];  // [16,2048,3]
    const float* rotv = (const float*)d_in[2];  // [4,16,3]
    const float* trav = (const float*)d_in[3];  // [4,16,3]
    const float* scal = (const float*)d_in[4];  // [4,16]
    float* out = (float*)d_out;                 // [4,16]

    // ws: Yb 2 MB | Ya 4 MB | Xb 0.5 MB | Xa 1 MB  = 7.5 MB
    char* ws = (char*)d_ws;
    uint4* Yb = (uint4*)ws;
    uint4* Ya = (uint4*)(ws + (size_t)NPAIR * NPTS * 16);
    uint4* Xb = (uint4*)(ws + (size_t)NPAIR * NPTS * 48);
    uint4* Xa = (uint4*)(ws + (size_t)NPAIR * NPTS * 48 + (size_t)IDIM * NPTS * 16);

    dim3 pgrid(NPAIR + IDIM, PSPLIT);
    prep<<<pgrid, THREADS, 0, stream>>>(src, tgt, rotv, trav, scal, Yb, Ya, Xb, Xa, out);

    dim3 grid(NPAIR, RBLK, 2);
    chamfer_main<<<grid, THREADS, 0, stream>>>(Yb, Ya, Xb, Xa, out, 0.0f);
}